// Round 5
// baseline (239.285 us; speedup 1.0000x reference)
//
#include <hip/hip_runtime.h>
#include <hip/hip_bf16.h>

// Deformable conv v3: same fused structure as v2, occupancy experiment.
//   k_pad_prep: pad/transpose x -> NHWC bf16 (blocks 0..1039) + weight pack
//               (blocks 1040..1066)
//   k_fused:    __launch_bounds__(256,8) -> 8 blocks/CU (was 4; latency-bound
//               at 47% occupancy, VALUBusy 19.6%, MfmaUtil 5%)
//
// ws layout (bytes):
//   [0)          xpT      bf16 [8][130][130][64] = 17,305,600
//   [17305600)   Bpack    bf16 [18][4][64][8]    =     73,728
//   [17379328)   wOffPack bf16 [18][2][64][8]    =     36,864

#define PH   130
#define CIN  64
#define COUT 64

typedef __attribute__((ext_vector_type(8))) __bf16 bf16x8;
typedef __attribute__((ext_vector_type(4))) float  f32x4;

__device__ __forceinline__ short f2bf(float f) {
  return __builtin_bit_cast(short, __float2bfloat16(f));
}
__device__ __forceinline__ float blo(unsigned u) {
  return __builtin_bit_cast(float, u << 16);
}
__device__ __forceinline__ float bhi(unsigned u) {
  return __builtin_bit_cast(float, u & 0xffff0000u);
}
__device__ __forceinline__ unsigned packbf(float a, float b) {
  unsigned lo16 = (unsigned short)__builtin_bit_cast(unsigned short, __float2bfloat16(a));
  unsigned hi16 = (unsigned short)__builtin_bit_cast(unsigned short, __float2bfloat16(b));
  return lo16 | (hi16 << 16);
}

// ---------------- K1: pad+transpose (blocks <1040) and weight pack (rest) ---
__global__ __launch_bounds__(256) void k_pad_prep(
    const float* __restrict__ x, const float* __restrict__ w_off,
    const float* __restrict__ w_conv, __hip_bfloat16* __restrict__ xpT,
    short* __restrict__ Bpack, short* __restrict__ wOffPack) {
  __shared__ __hip_bfloat16 tile[128 * 64];  // [w][c], c XOR-swizzled by (w>>2)&7
  int bid = blockIdx.x;
  int tid = threadIdx.x;
  if (bid < 8 * PH) {
    // ---- pad + NCHW->NHWC transpose, fp32 -> bf16
    int n = bid / PH;
    int y = bid % PH;
    bool interior = (y >= 1 && y <= 128);
    if (interior) {
      for (int i = tid; i < 2048; i += 256) {       // 64 ch x 32 float4
        int c  = i >> 5;
        int w4 = (i & 31) << 2;
        float4 v = *(const float4*)(x + (((size_t)(n * 64 + c) * 128) + (y - 1)) * 128 + w4);
        int sw = (i & 7) << 3;
        tile[(w4 + 0) * 64 + (c ^ sw)] = __float2bfloat16(v.x);
        tile[(w4 + 1) * 64 + (c ^ sw)] = __float2bfloat16(v.y);
        tile[(w4 + 2) * 64 + (c ^ sw)] = __float2bfloat16(v.z);
        tile[(w4 + 3) * 64 + (c ^ sw)] = __float2bfloat16(v.w);
      }
    }
    __syncthreads();
    __hip_bfloat16* dst = xpT + (size_t)(n * PH + y) * PH * CIN;
    bool zrow = (y == 0 || y == PH - 1);
    for (int i = tid; i < 1040; i += 256) {          // 130 px * 64 ch / 8
      int px = i >> 3;
      int c0 = (i & 7) << 3;
      uint4 v;
      if (zrow || px == 0 || px == PH - 1) {
        v = make_uint4(0u, 0u, 0u, 0u);
      } else {
        int pxi = px - 1;
        int c0s = c0 ^ (((pxi >> 2) & 7) << 3);
        v = *(const uint4*)&tile[pxi * 64 + c0s];
      }
      *(uint4*)(dst + (size_t)i * 8) = v;
    }
  } else {
    // ---- weight pack into MFMA B-fragment order:
    // frag elem i, lane l, k-step kk: k = kk*32+(l>>4)*8+i, tap=k/64, ci=k%64,
    // co = nt*16+(l&15).
    int t = (bid - 8 * PH) * 256 + tid;
    if (t < 18 * 4 * 64) {
      int lane = t & 63;
      int nt   = (t >> 6) & 3;
      int kk   = t >> 8;
      int co   = nt * 16 + (lane & 15);
      int kbase = kk * 32 + ((lane >> 4) << 3);
      short v[8];
#pragma unroll
      for (int i = 0; i < 8; ++i) {
        int k = kbase + i;
        v[i] = f2bf(w_conv[(size_t)(co * 64 + (k & 63)) * 9 + (k >> 6)]);
      }
      *(uint4*)(Bpack + (size_t)t * 8) = *(const uint4*)v;
    }
    int u = t - 18 * 4 * 64;
    if (u >= 0 && u < 18 * 2 * 64) {
      int lane = u & 63;
      int nt   = (u >> 6) & 1;
      int kk   = u >> 7;
      int co   = nt * 16 + (lane & 15);
      int kbase = kk * 32 + ((lane >> 4) << 3);
      short v[8];
#pragma unroll
      for (int i = 0; i < 8; ++i) {
        int k = kbase + i;
        v[i] = (co < 18) ? f2bf(w_off[(size_t)(co * 64 + (k & 63)) * 9 + (k >> 6)]) : (short)0;
      }
      *(uint4*)(wOffPack + (size_t)u * 8) = *(const uint4*)v;
    }
  }
}

// ---------------- K2: fused offset conv + deform sample + main conv ---------
// 8 blocks/CU (grid 2048 = 8 x 256 CU): latency-bound gathers need ~8 waves/SIMD.
__global__ __launch_bounds__(256, 8) void k_fused(
    const __hip_bfloat16* __restrict__ xpT, const short* __restrict__ Bpack,
    const short* __restrict__ wOffPack, const float* __restrict__ b_off,
    const float* __restrict__ b_conv, float* __restrict__ out) {
  __shared__ __attribute__((aligned(16))) char shraw[17408];
  float* offsLds = (float*)shraw;            // [64 pix][20]  (co 0..17 used)
  int4*  metaLds = (int4*)(shraw + 5120);    // [64 pix][9 taps]
  float* olds    = (float*)shraw;            // [64 pix][68]  (epilogue reuse)

  int bid = blockIdx.x;                      // 8*128*2
  int wh  = bid & 1;
  int h   = (bid >> 1) & 127;
  int n   = bid >> 8;
  int w0  = wh << 6;
  int tid = threadIdx.x, wv = tid >> 6, lane = tid & 63;
  int p = lane & 15, oct = lane >> 4;
  const char* xbB = (const char*)(xpT + (size_t)n * PH * PH * CIN);

  // ---- P1: offset conv. M=16 pixels/wave, N=32 (co<18 live), K=576.
  {
    f32x4 ao0 = {0.f, 0.f, 0.f, 0.f}, ao1 = ao0;
    int wpix = w0 + wv * 16 + p;
    const bf16x8* Wo = (const bf16x8*)wOffPack;
#pragma unroll
    for (int kk = 0; kk < 18; ++kk) {
      int tap = kk >> 1;
      int ky = tap / 3, kx = tap - (tap / 3) * 3;
      int ci0 = ((kk & 1) << 5) + (oct << 3);
      int off = (((h + ky) * PH + (wpix + kx)) * CIN + ci0) * 2;
      bf16x8 a  = *(const bf16x8*)(xbB + off);
      bf16x8 b0 = Wo[(kk * 2 + 0) * 64 + lane];
      bf16x8 b1 = Wo[(kk * 2 + 1) * 64 + lane];
      ao0 = __builtin_amdgcn_mfma_f32_16x16x32_bf16(a, b0, ao0, 0, 0, 0);
      ao1 = __builtin_amdgcn_mfma_f32_16x16x32_bf16(a, b1, ao1, 0, 0, 0);
    }
    // C/D: col = lane&15 (=co), row = oct*4+r (=pixel within wave's 16)
    int co = lane & 15;
    float bo0 = b_off[co];
#pragma unroll
    for (int r = 0; r < 4; ++r)
      offsLds[(wv * 16 + oct * 4 + r) * 20 + co] = ao0[r] + bo0;
    if (co < 2) {
      float bo1 = b_off[16 + co];
#pragma unroll
      for (int r = 0; r < 4; ++r)
        offsLds[(wv * 16 + oct * 4 + r) * 20 + 16 + co] = ao1[r] + bo1;
    }
  }
  __syncthreads();

  // ---- P2: sampling metadata, one (pixel,tap) per thread.
  for (int t = tid; t < 576; t += 256) {
    int pix = t / 9, tap = t - pix * 9;
    int ky = tap / 3, kx = tap - (tap / 3) * 3;
    float cx = offsLds[pix * 20 + tap]     + (float)(w0 + pix + kx);
    float cy = offsLds[pix * 20 + 9 + tap] + (float)(h + ky);
    cx = fminf(fmaxf(cx, 0.f), 129.f);
    cy = fminf(fmaxf(cy, 0.f), 129.f);
    float x0f = floorf(cx), y0f = floorf(cy);
    int x0 = (int)x0f, y0 = (int)y0f;
    float wx = cx - x0f, wy = cy - y0f;
    int baseB = (y0 * PH + x0) << 7;                    // *128 bytes (64ch*2B)
    int dxdy = ((x0 < PH - 1) ? 128 : 0) | (((y0 < PH - 1) ? PH * 128 : 0) << 16);
    metaLds[t] = make_int4(baseB, __builtin_bit_cast(int, wx),
                           __builtin_bit_cast(int, wy), dxdy);
  }
  __syncthreads();

  // ---- P3: main conv, deformed A-frags in registers.
  f32x4 acc0 = {0.f, 0.f, 0.f, 0.f}, acc1 = acc0, acc2 = acc0, acc3 = acc0;
  const bf16x8* Bp = (const bf16x8*)Bpack;
  int mbase = (wv * 16 + p) * 9;
#pragma unroll
  for (int tap = 0; tap < 9; ++tap) {
    int4 mt = metaLds[mbase + tap];
    float wx = __builtin_bit_cast(float, mt.y);
    float wy = __builtin_bit_cast(float, mt.z);
    int dx = mt.w & 0xffff;
    int dy = (mt.w >> 16) & 0xffff;
    float w11 = wx * wy;
    float w01 = wx - w11;          // wx*(1-wy)
    float w10 = wy - w11;          // (1-wx)*wy
    float w00 = 1.f - wx - w10;    // (1-wx)*(1-wy)
    const char* pb = xbB + (mt.x + (oct << 4));
#pragma unroll
    for (int half = 0; half < 2; ++half) {
      const char* pc = pb + (half << 6);
      uint4 q00 = *(const uint4*)(pc);
      uint4 q01 = *(const uint4*)(pc + dx);
      uint4 q10 = *(const uint4*)(pc + dy);
      uint4 q11 = *(const uint4*)(pc + dx + dy);
      unsigned av[4];
#pragma unroll
      for (int j = 0; j < 4; ++j) {
        unsigned u00 = ((const unsigned*)&q00)[j];
        unsigned u01 = ((const unsigned*)&q01)[j];
        unsigned u10 = ((const unsigned*)&q10)[j];
        unsigned u11 = ((const unsigned*)&q11)[j];
        float sl = blo(u00) * w00 + blo(u01) * w01 + blo(u10) * w10 + blo(u11) * w11;
        float sh = bhi(u00) * w00 + bhi(u01) * w01 + bhi(u10) * w10 + bhi(u11) * w11;
        av[j] = packbf(sl, sh);
      }
      bf16x8 a = __builtin_bit_cast(bf16x8, *(uint4*)av);
      int kk = tap * 2 + half;
      bf16x8 b0 = Bp[(kk * 4 + 0) * 64 + lane];
      bf16x8 b1 = Bp[(kk * 4 + 1) * 64 + lane];
      bf16x8 b2 = Bp[(kk * 4 + 2) * 64 + lane];
      bf16x8 b3 = Bp[(kk * 4 + 3) * 64 + lane];
      acc0 = __builtin_amdgcn_mfma_f32_16x16x32_bf16(a, b0, acc0, 0, 0, 0);
      acc1 = __builtin_amdgcn_mfma_f32_16x16x32_bf16(a, b1, acc1, 0, 0, 0);
      acc2 = __builtin_amdgcn_mfma_f32_16x16x32_bf16(a, b2, acc2, 0, 0, 0);
      acc3 = __builtin_amdgcn_mfma_f32_16x16x32_bf16(a, b3, acc3, 0, 0, 0);
    }
  }
  __syncthreads();

  // ---- P4: epilogue via LDS transpose (pitch 68), coalesced NCHW store.
  int prow0 = wv * 16 + (oct << 2);
#pragma unroll
  for (int r = 0; r < 4; ++r) {
    olds[(prow0 + r) * 68 + p     ] = acc0[r];
    olds[(prow0 + r) * 68 + p + 16] = acc1[r];
    olds[(prow0 + r) * 68 + p + 32] = acc2[r];
    olds[(prow0 + r) * 68 + p + 48] = acc3[r];
  }
  __syncthreads();
  float* ob = out + (size_t)n * COUT * 16384 + (size_t)h * 128 + w0;
  for (int i = tid; i < 4096; i += 256) {
    int co = i >> 6, px = i & 63;
    ob[(size_t)co * 16384 + px] = olds[px * 68 + co] + b_conv[co];
  }
}

// ---------------------------------------------------------------------------
extern "C" void kernel_launch(void* const* d_in, const int* in_sizes, int n_in,
                              void* d_out, int out_size, void* d_ws, size_t ws_size,
                              hipStream_t stream) {
  const float* x      = (const float*)d_in[0];
  const float* w_off  = (const float*)d_in[1];
  const float* b_off  = (const float*)d_in[2];
  const float* w_conv = (const float*)d_in[3];
  const float* b_conv = (const float*)d_in[4];
  float* out = (float*)d_out;

  char* ws = (char*)d_ws;
  __hip_bfloat16* xpT = (__hip_bfloat16*)ws;             // 17,305,600 B
  short* Bpack    = (short*)(ws + 17305600);             //     73,728 B
  short* wOffPack = (short*)(ws + 17305600 + 73728);     //     36,864 B

  k_pad_prep<<<dim3(8 * PH + 27), dim3(256), 0, stream>>>(x, w_off, w_conv,
                                                          xpT, Bpack, wOffPack);
  k_fused<<<dim3(2048), dim3(256), 0, stream>>>(xpT, Bpack, wOffPack, b_off, b_conv, out);
}

// Round 8
// 193.318 us; speedup vs baseline: 1.2378x; 1.2378x over previous
//
#include <hip/hip_runtime.h>
#include <hip/hip_bf16.h>

// Deformable conv v4: occupancy midpoint. Round-4 (bounds 256,4): 4 blk/CU,
// VGPR 48, no spill, 112us. Round-5 (256,8): VGPR crushed to 32 -> scratch
// spills (+130MB writes, +270MB fetch), 157us. v4 = (256,6): VGPR cap 85 ->
// compiler's natural 48 fits, 6+ blocks/CU resident, no spill.
//
// ws layout (bytes):
//   [0)          xpT      bf16 [8][130][130][64] = 17,305,600
//   [17305600)   Bpack    bf16 [18][4][64][8]    =     73,728
//   [17379328)   wOffPack bf16 [18][2][64][8]    =     36,864

#define PH   130
#define CIN  64
#define COUT 64

typedef __attribute__((ext_vector_type(8))) __bf16 bf16x8;
typedef __attribute__((ext_vector_type(4))) float  f32x4;

__device__ __forceinline__ short f2bf(float f) {
  return __builtin_bit_cast(short, __float2bfloat16(f));
}
__device__ __forceinline__ float blo(unsigned u) {
  return __builtin_bit_cast(float, u << 16);
}
__device__ __forceinline__ float bhi(unsigned u) {
  return __builtin_bit_cast(float, u & 0xffff0000u);
}
__device__ __forceinline__ unsigned packbf(float a, float b) {
  unsigned lo16 = (unsigned short)__builtin_bit_cast(unsigned short, __float2bfloat16(a));
  unsigned hi16 = (unsigned short)__builtin_bit_cast(unsigned short, __float2bfloat16(b));
  return lo16 | (hi16 << 16);
}

// ---------------- K1: pad+transpose (blocks <1040) and weight pack (rest) ---
__global__ __launch_bounds__(256) void k_pad_prep(
    const float* __restrict__ x, const float* __restrict__ w_off,
    const float* __restrict__ w_conv, __hip_bfloat16* __restrict__ xpT,
    short* __restrict__ Bpack, short* __restrict__ wOffPack) {
  __shared__ __hip_bfloat16 tile[128 * 64];  // [w][c], c XOR-swizzled by (w>>2)&7
  int bid = blockIdx.x;
  int tid = threadIdx.x;
  if (bid < 8 * PH) {
    // ---- pad + NCHW->NHWC transpose, fp32 -> bf16
    int n = bid / PH;
    int y = bid % PH;
    bool interior = (y >= 1 && y <= 128);
    if (interior) {
      for (int i = tid; i < 2048; i += 256) {       // 64 ch x 32 float4
        int c  = i >> 5;
        int w4 = (i & 31) << 2;
        float4 v = *(const float4*)(x + (((size_t)(n * 64 + c) * 128) + (y - 1)) * 128 + w4);
        int sw = (i & 7) << 3;
        tile[(w4 + 0) * 64 + (c ^ sw)] = __float2bfloat16(v.x);
        tile[(w4 + 1) * 64 + (c ^ sw)] = __float2bfloat16(v.y);
        tile[(w4 + 2) * 64 + (c ^ sw)] = __float2bfloat16(v.z);
        tile[(w4 + 3) * 64 + (c ^ sw)] = __float2bfloat16(v.w);
      }
    }
    __syncthreads();
    __hip_bfloat16* dst = xpT + (size_t)(n * PH + y) * PH * CIN;
    bool zrow = (y == 0 || y == PH - 1);
    for (int i = tid; i < 1040; i += 256) {          // 130 px * 64 ch / 8
      int px = i >> 3;
      int c0 = (i & 7) << 3;
      uint4 v;
      if (zrow || px == 0 || px == PH - 1) {
        v = make_uint4(0u, 0u, 0u, 0u);
      } else {
        int pxi = px - 1;
        int c0s = c0 ^ (((pxi >> 2) & 7) << 3);
        v = *(const uint4*)&tile[pxi * 64 + c0s];
      }
      *(uint4*)(dst + (size_t)i * 8) = v;
    }
  } else {
    // ---- weight pack into MFMA B-fragment order:
    // frag elem i, lane l, k-step kk: k = kk*32+(l>>4)*8+i, tap=k/64, ci=k%64,
    // co = nt*16+(l&15).
    int t = (bid - 8 * PH) * 256 + tid;
    if (t < 18 * 4 * 64) {
      int lane = t & 63;
      int nt   = (t >> 6) & 3;
      int kk   = t >> 8;
      int co   = nt * 16 + (lane & 15);
      int kbase = kk * 32 + ((lane >> 4) << 3);
      short v[8];
#pragma unroll
      for (int i = 0; i < 8; ++i) {
        int k = kbase + i;
        v[i] = f2bf(w_conv[(size_t)(co * 64 + (k & 63)) * 9 + (k >> 6)]);
      }
      *(uint4*)(Bpack + (size_t)t * 8) = *(const uint4*)v;
    }
    int u = t - 18 * 4 * 64;
    if (u >= 0 && u < 18 * 2 * 64) {
      int lane = u & 63;
      int nt   = (u >> 6) & 1;
      int kk   = u >> 7;
      int co   = nt * 16 + (lane & 15);
      int kbase = kk * 32 + ((lane >> 4) << 3);
      short v[8];
#pragma unroll
      for (int i = 0; i < 8; ++i) {
        int k = kbase + i;
        v[i] = (co < 18) ? f2bf(w_off[(size_t)(co * 64 + (k & 63)) * 9 + (k >> 6)]) : (short)0;
      }
      *(uint4*)(wOffPack + (size_t)u * 8) = *(const uint4*)v;
    }
  }
}

// ---------------- K2: fused offset conv + deform sample + main conv ---------
// (256,6): min 6 waves/SIMD resident, VGPR cap 85 -> natural 48, no spill.
__global__ __launch_bounds__(256, 6) void k_fused(
    const __hip_bfloat16* __restrict__ xpT, const short* __restrict__ Bpack,
    const short* __restrict__ wOffPack, const float* __restrict__ b_off,
    const float* __restrict__ b_conv, float* __restrict__ out) {
  __shared__ __attribute__((aligned(16))) char shraw[17408];
  float* offsLds = (float*)shraw;            // [64 pix][20]  (co 0..17 used)
  int4*  metaLds = (int4*)(shraw + 5120);    // [64 pix][9 taps]
  float* olds    = (float*)shraw;            // [64 pix][68]  (epilogue reuse)

  int bid = blockIdx.x;                      // 8*128*2
  int wh  = bid & 1;
  int h   = (bid >> 1) & 127;
  int n   = bid >> 8;
  int w0  = wh << 6;
  int tid = threadIdx.x, wv = tid >> 6, lane = tid & 63;
  int p = lane & 15, oct = lane >> 4;
  const char* xbB = (const char*)(xpT + (size_t)n * PH * PH * CIN);

  // ---- P1: offset conv. M=16 pixels/wave, N=32 (co<18 live), K=576.
  {
    f32x4 ao0 = {0.f, 0.f, 0.f, 0.f}, ao1 = ao0;
    int wpix = w0 + wv * 16 + p;
    const bf16x8* Wo = (const bf16x8*)wOffPack;
#pragma unroll
    for (int kk = 0; kk < 18; ++kk) {
      int tap = kk >> 1;
      int ky = tap / 3, kx = tap - (tap / 3) * 3;
      int ci0 = ((kk & 1) << 5) + (oct << 3);
      int off = (((h + ky) * PH + (wpix + kx)) * CIN + ci0) * 2;
      bf16x8 a  = *(const bf16x8*)(xbB + off);
      bf16x8 b0 = Wo[(kk * 2 + 0) * 64 + lane];
      bf16x8 b1 = Wo[(kk * 2 + 1) * 64 + lane];
      ao0 = __builtin_amdgcn_mfma_f32_16x16x32_bf16(a, b0, ao0, 0, 0, 0);
      ao1 = __builtin_amdgcn_mfma_f32_16x16x32_bf16(a, b1, ao1, 0, 0, 0);
    }
    // C/D: col = lane&15 (=co), row = oct*4+r (=pixel within wave's 16)
    int co = lane & 15;
    float bo0 = b_off[co];
#pragma unroll
    for (int r = 0; r < 4; ++r)
      offsLds[(wv * 16 + oct * 4 + r) * 20 + co] = ao0[r] + bo0;
    if (co < 2) {
      float bo1 = b_off[16 + co];
#pragma unroll
      for (int r = 0; r < 4; ++r)
        offsLds[(wv * 16 + oct * 4 + r) * 20 + 16 + co] = ao1[r] + bo1;
    }
  }
  __syncthreads();

  // ---- P2: sampling metadata, one (pixel,tap) per thread.
  for (int t = tid; t < 576; t += 256) {
    int pix = t / 9, tap = t - pix * 9;
    int ky = tap / 3, kx = tap - (tap / 3) * 3;
    float cx = offsLds[pix * 20 + tap]     + (float)(w0 + pix + kx);
    float cy = offsLds[pix * 20 + 9 + tap] + (float)(h + ky);
    cx = fminf(fmaxf(cx, 0.f), 129.f);
    cy = fminf(fmaxf(cy, 0.f), 129.f);
    float x0f = floorf(cx), y0f = floorf(cy);
    int x0 = (int)x0f, y0 = (int)y0f;
    float wx = cx - x0f, wy = cy - y0f;
    int baseB = (y0 * PH + x0) << 7;                    // *128 bytes (64ch*2B)
    int dxdy = ((x0 < PH - 1) ? 128 : 0) | (((y0 < PH - 1) ? PH * 128 : 0) << 16);
    metaLds[t] = make_int4(baseB, __builtin_bit_cast(int, wx),
                           __builtin_bit_cast(int, wy), dxdy);
  }
  __syncthreads();

  // ---- P3: main conv, deformed A-frags in registers.
  f32x4 acc0 = {0.f, 0.f, 0.f, 0.f}, acc1 = acc0, acc2 = acc0, acc3 = acc0;
  const bf16x8* Bp = (const bf16x8*)Bpack;
  int mbase = (wv * 16 + p) * 9;
#pragma unroll
  for (int tap = 0; tap < 9; ++tap) {
    int4 mt = metaLds[mbase + tap];
    float wx = __builtin_bit_cast(float, mt.y);
    float wy = __builtin_bit_cast(float, mt.z);
    int dx = mt.w & 0xffff;
    int dy = (mt.w >> 16) & 0xffff;
    float w11 = wx * wy;
    float w01 = wx - w11;          // wx*(1-wy)
    float w10 = wy - w11;          // (1-wx)*wy
    float w00 = 1.f - wx - w10;    // (1-wx)*(1-wy)
    const char* pb = xbB + (mt.x + (oct << 4));
#pragma unroll
    for (int half = 0; half < 2; ++half) {
      const char* pc = pb + (half << 6);
      uint4 q00 = *(const uint4*)(pc);
      uint4 q01 = *(const uint4*)(pc + dx);
      uint4 q10 = *(const uint4*)(pc + dy);
      uint4 q11 = *(const uint4*)(pc + dx + dy);
      unsigned av[4];
#pragma unroll
      for (int j = 0; j < 4; ++j) {
        unsigned u00 = ((const unsigned*)&q00)[j];
        unsigned u01 = ((const unsigned*)&q01)[j];
        unsigned u10 = ((const unsigned*)&q10)[j];
        unsigned u11 = ((const unsigned*)&q11)[j];
        float sl = blo(u00) * w00 + blo(u01) * w01 + blo(u10) * w10 + blo(u11) * w11;
        float sh = bhi(u00) * w00 + bhi(u01) * w01 + bhi(u10) * w10 + bhi(u11) * w11;
        av[j] = packbf(sl, sh);
      }
      bf16x8 a = __builtin_bit_cast(bf16x8, *(uint4*)av);
      int kk = tap * 2 + half;
      bf16x8 b0 = Bp[(kk * 4 + 0) * 64 + lane];
      bf16x8 b1 = Bp[(kk * 4 + 1) * 64 + lane];
      bf16x8 b2 = Bp[(kk * 4 + 2) * 64 + lane];
      bf16x8 b3 = Bp[(kk * 4 + 3) * 64 + lane];
      acc0 = __builtin_amdgcn_mfma_f32_16x16x32_bf16(a, b0, acc0, 0, 0, 0);
      acc1 = __builtin_amdgcn_mfma_f32_16x16x32_bf16(a, b1, acc1, 0, 0, 0);
      acc2 = __builtin_amdgcn_mfma_f32_16x16x32_bf16(a, b2, acc2, 0, 0, 0);
      acc3 = __builtin_amdgcn_mfma_f32_16x16x32_bf16(a, b3, acc3, 0, 0, 0);
    }
  }
  __syncthreads();

  // ---- P4: epilogue via LDS transpose (pitch 68), coalesced NCHW store.
  int prow0 = wv * 16 + (oct << 2);
#pragma unroll
  for (int r = 0; r < 4; ++r) {
    olds[(prow0 + r) * 68 + p     ] = acc0[r];
    olds[(prow0 + r) * 68 + p + 16] = acc1[r];
    olds[(prow0 + r) * 68 + p + 32] = acc2[r];
    olds[(prow0 + r) * 68 + p + 48] = acc3[r];
  }
  __syncthreads();
  float* ob = out + (size_t)n * COUT * 16384 + (size_t)h * 128 + w0;
  for (int i = tid; i < 4096; i += 256) {
    int co = i >> 6, px = i & 63;
    ob[(size_t)co * 16384 + px] = olds[px * 68 + co] + b_conv[co];
  }
}

// ---------------------------------------------------------------------------
extern "C" void kernel_launch(void* const* d_in, const int* in_sizes, int n_in,
                              void* d_out, int out_size, void* d_ws, size_t ws_size,
                              hipStream_t stream) {
  const float* x      = (const float*)d_in[0];
  const float* w_off  = (const float*)d_in[1];
  const float* b_off  = (const float*)d_in[2];
  const float* w_conv = (const float*)d_in[3];
  const float* b_conv = (const float*)d_in[4];
  float* out = (float*)d_out;

  char* ws = (char*)d_ws;
  __hip_bfloat16* xpT = (__hip_bfloat16*)ws;             // 17,305,600 B
  short* Bpack    = (short*)(ws + 17305600);             //     73,728 B
  short* wOffPack = (short*)(ws + 17305600 + 73728);     //     36,864 B

  k_pad_prep<<<dim3(8 * PH + 27), dim3(256), 0, stream>>>(x, w_off, w_conv,
                                                          xpT, Bpack, wOffPack);
  k_fused<<<dim3(2048), dim3(256), 0, stream>>>(xpT, Bpack, wOffPack, b_off, b_conv, out);
}

// Round 9
// 176.645 us; speedup vs baseline: 1.3546x; 1.0944x over previous
//
#include <hip/hip_runtime.h>
#include <hip/hip_bf16.h>

// Deformable conv v5: TCP-transaction reduction. Round-8 showed dur invariant
// to occupancy (47->54%, both 112us) with all pipes idle => per-CU vector-mem
// request pipe saturated (~16 line-transactions per 16B/lane load, hit or
// miss). Biggest redundant term: every wave re-reads the same Bpack/wOffPack
// fragments (73.7KB + 36.9KB) from L1/L2. v5 stages them into LDS once per
// block (reg-staged double-buffer: global load -> ds_write), cutting B-path
// transactions 4x. Gathers (already at 8-line/px/tap minimum) untouched.
//
// ws layout (bytes):
//   [0)          xpT      bf16 [8][130][130][64] = 17,305,600
//   [17305600)   Bpack    bf16 [18][4][64][8]    =     73,728
//   [17379328)   wOffPack bf16 [18][2][64][8]    =     36,864

#define PH   130
#define CIN  64
#define COUT 64

typedef __attribute__((ext_vector_type(8))) __bf16 bf16x8;
typedef __attribute__((ext_vector_type(4))) float  f32x4;

__device__ __forceinline__ short f2bf(float f) {
  return __builtin_bit_cast(short, __float2bfloat16(f));
}
__device__ __forceinline__ float blo(unsigned u) {
  return __builtin_bit_cast(float, u << 16);
}
__device__ __forceinline__ float bhi(unsigned u) {
  return __builtin_bit_cast(float, u & 0xffff0000u);
}
__device__ __forceinline__ unsigned packbf(float a, float b) {
  unsigned lo16 = (unsigned short)__builtin_bit_cast(unsigned short, __float2bfloat16(a));
  unsigned hi16 = (unsigned short)__builtin_bit_cast(unsigned short, __float2bfloat16(b));
  return lo16 | (hi16 << 16);
}

// ---------------- K1: pad+transpose (blocks <1040) and weight pack (rest) ---
__global__ __launch_bounds__(256) void k_pad_prep(
    const float* __restrict__ x, const float* __restrict__ w_off,
    const float* __restrict__ w_conv, __hip_bfloat16* __restrict__ xpT,
    short* __restrict__ Bpack, short* __restrict__ wOffPack) {
  __shared__ __hip_bfloat16 tile[128 * 64];  // [w][c], c XOR-swizzled by (w>>2)&7
  int bid = blockIdx.x;
  int tid = threadIdx.x;
  if (bid < 8 * PH) {
    // ---- pad + NCHW->NHWC transpose, fp32 -> bf16
    int n = bid / PH;
    int y = bid % PH;
    bool interior = (y >= 1 && y <= 128);
    if (interior) {
      for (int i = tid; i < 2048; i += 256) {       // 64 ch x 32 float4
        int c  = i >> 5;
        int w4 = (i & 31) << 2;
        float4 v = *(const float4*)(x + (((size_t)(n * 64 + c) * 128) + (y - 1)) * 128 + w4);
        int sw = (i & 7) << 3;
        tile[(w4 + 0) * 64 + (c ^ sw)] = __float2bfloat16(v.x);
        tile[(w4 + 1) * 64 + (c ^ sw)] = __float2bfloat16(v.y);
        tile[(w4 + 2) * 64 + (c ^ sw)] = __float2bfloat16(v.z);
        tile[(w4 + 3) * 64 + (c ^ sw)] = __float2bfloat16(v.w);
      }
    }
    __syncthreads();
    __hip_bfloat16* dst = xpT + (size_t)(n * PH + y) * PH * CIN;
    bool zrow = (y == 0 || y == PH - 1);
    for (int i = tid; i < 1040; i += 256) {          // 130 px * 64 ch / 8
      int px = i >> 3;
      int c0 = (i & 7) << 3;
      uint4 v;
      if (zrow || px == 0 || px == PH - 1) {
        v = make_uint4(0u, 0u, 0u, 0u);
      } else {
        int pxi = px - 1;
        int c0s = c0 ^ (((pxi >> 2) & 7) << 3);
        v = *(const uint4*)&tile[pxi * 64 + c0s];
      }
      *(uint4*)(dst + (size_t)i * 8) = v;
    }
  } else {
    // ---- weight pack into MFMA B-fragment order:
    // frag elem i, lane l, k-step kk: k = kk*32+(l>>4)*8+i, tap=k/64, ci=k%64,
    // co = nt*16+(l&15).
    int t = (bid - 8 * PH) * 256 + tid;
    if (t < 18 * 4 * 64) {
      int lane = t & 63;
      int nt   = (t >> 6) & 3;
      int kk   = t >> 8;
      int co   = nt * 16 + (lane & 15);
      int kbase = kk * 32 + ((lane >> 4) << 3);
      short v[8];
#pragma unroll
      for (int i = 0; i < 8; ++i) {
        int k = kbase + i;
        v[i] = f2bf(w_conv[(size_t)(co * 64 + (k & 63)) * 9 + (k >> 6)]);
      }
      *(uint4*)(Bpack + (size_t)t * 8) = *(const uint4*)v;
    }
    int u = t - 18 * 4 * 64;
    if (u >= 0 && u < 18 * 2 * 64) {
      int lane = u & 63;
      int nt   = (u >> 6) & 1;
      int kk   = u >> 7;
      int co   = nt * 16 + (lane & 15);
      int kbase = kk * 32 + ((lane >> 4) << 3);
      short v[8];
#pragma unroll
      for (int i = 0; i < 8; ++i) {
        int k = kbase + i;
        v[i] = (co < 18) ? f2bf(w_off[(size_t)(co * 64 + (k & 63)) * 9 + (k >> 6)]) : (short)0;
      }
      *(uint4*)(wOffPack + (size_t)u * 8) = *(const uint4*)v;
    }
  }
}

// ---------------- K2: fused offset conv + deform sample + main conv ---------
// LDS map (30,720 B total):
//   offsLds f32[64][20]   [0,     5120)   P1 out / P2 in
//   metaLds int4[64][9]   [5120, 14336)   P2 out / P3 in
//   stg (weight staging)  [14336, 30720)  P1: 2x4KB dbuf; P3: 2x8KB dbuf
//   olds f32[64][68]      [0,    17408)   epilogue only (stg dead by then)
__global__ __launch_bounds__(256, 4) void k_fused(
    const __hip_bfloat16* __restrict__ xpT, const short* __restrict__ Bpack,
    const short* __restrict__ wOffPack, const float* __restrict__ b_off,
    const float* __restrict__ b_conv, float* __restrict__ out) {
  __shared__ __attribute__((aligned(16))) char shraw[30720];
  float* offsLds = (float*)shraw;
  int4*  metaLds = (int4*)(shraw + 5120);
  char*  stg     = shraw + 14336;
  float* olds    = (float*)shraw;

  int bid = blockIdx.x;                      // 8*128*2
  int wh  = bid & 1;
  int h   = (bid >> 1) & 127;
  int n   = bid >> 8;
  int w0  = wh << 6;
  int tid = threadIdx.x, wv = tid >> 6, lane = tid & 63;
  int p = lane & 15, oct = lane >> 4;
  const char* xbB = (const char*)(xpT + (size_t)n * PH * PH * CIN);

  // ---- P1: offset conv. M=16 pixels/wave, N=32 (co<18 live), K=576.
  // wOff frags staged through LDS per tap-pair (4KB), double-buffered.
  {
    const char* wOffB = (const char*)wOffPack;
    {
      uint4 s = *(const uint4*)(wOffB + tid * 16);
      *(uint4*)(stg + tid * 16) = s;
    }
    __syncthreads();
    f32x4 ao0 = {0.f, 0.f, 0.f, 0.f}, ao1 = ao0;
    int wpix = w0 + wv * 16 + p;
    for (int pr = 0; pr < 9; ++pr) {         // pr == tap; kk = 2*pr + sub
      uint4 nxt;
      if (pr < 8) nxt = *(const uint4*)(wOffB + (pr + 1) * 4096 + tid * 16);
      const char* bb = stg + (pr & 1) * 4096;
      int ky = pr / 3, kx = pr - (pr / 3) * 3;
#pragma unroll
      for (int sub = 0; sub < 2; ++sub) {
        int ci0 = (sub << 5) + (oct << 3);
        int off = (((h + ky) * PH + (wpix + kx)) * CIN + ci0) * 2;
        bf16x8 a  = *(const bf16x8*)(xbB + off);
        bf16x8 b0 = *(const bf16x8*)(bb + sub * 2048 + lane * 16);
        bf16x8 b1 = *(const bf16x8*)(bb + sub * 2048 + 1024 + lane * 16);
        ao0 = __builtin_amdgcn_mfma_f32_16x16x32_bf16(a, b0, ao0, 0, 0, 0);
        ao1 = __builtin_amdgcn_mfma_f32_16x16x32_bf16(a, b1, ao1, 0, 0, 0);
      }
      if (pr < 8) *(uint4*)(stg + ((pr + 1) & 1) * 4096 + tid * 16) = nxt;
      __syncthreads();
    }
    // C/D: col = lane&15 (=co), row = oct*4+r (=pixel within wave's 16)
    int co = lane & 15;
    float bo0 = b_off[co];
#pragma unroll
    for (int r = 0; r < 4; ++r)
      offsLds[(wv * 16 + oct * 4 + r) * 20 + co] = ao0[r] + bo0;
    if (co < 2) {
      float bo1 = b_off[16 + co];
#pragma unroll
      for (int r = 0; r < 4; ++r)
        offsLds[(wv * 16 + oct * 4 + r) * 20 + 16 + co] = ao1[r] + bo1;
    }
  }
  __syncthreads();

  // ---- P2: sampling metadata, one (pixel,tap) per thread.
  for (int t = tid; t < 576; t += 256) {
    int pix = t / 9, tap = t - pix * 9;
    int ky = tap / 3, kx = tap - (tap / 3) * 3;
    float cx = offsLds[pix * 20 + tap]     + (float)(w0 + pix + kx);
    float cy = offsLds[pix * 20 + 9 + tap] + (float)(h + ky);
    cx = fminf(fmaxf(cx, 0.f), 129.f);
    cy = fminf(fmaxf(cy, 0.f), 129.f);
    float x0f = floorf(cx), y0f = floorf(cy);
    int x0 = (int)x0f, y0 = (int)y0f;
    float wx = cx - x0f, wy = cy - y0f;
    int baseB = (y0 * PH + x0) << 7;                    // *128 bytes (64ch*2B)
    int dxdy = ((x0 < PH - 1) ? 128 : 0) | (((y0 < PH - 1) ? PH * 128 : 0) << 16);
    metaLds[t] = make_int4(baseB, __builtin_bit_cast(int, wx),
                           __builtin_bit_cast(int, wy), dxdy);
  }
  __syncthreads();

  // ---- P3: main conv. B frags staged through LDS per tap (8KB), dbuf.
  f32x4 acc0 = {0.f, 0.f, 0.f, 0.f}, acc1 = acc0, acc2 = acc0, acc3 = acc0;
  const char* BpB = (const char*)Bpack;
  {
    uint4 s0 = *(const uint4*)(BpB + tid * 16);
    uint4 s1 = *(const uint4*)(BpB + 4096 + tid * 16);
    *(uint4*)(stg + tid * 16) = s0;
    *(uint4*)(stg + 4096 + tid * 16) = s1;
  }
  __syncthreads();
  int mbase = (wv * 16 + p) * 9;
#pragma unroll
  for (int tap = 0; tap < 9; ++tap) {
    uint4 n0, n1;
    if (tap < 8) {
      n0 = *(const uint4*)(BpB + (tap + 1) * 8192 + tid * 16);
      n1 = *(const uint4*)(BpB + (tap + 1) * 8192 + 4096 + tid * 16);
    }
    int4 mt = metaLds[mbase + tap];
    float wx = __builtin_bit_cast(float, mt.y);
    float wy = __builtin_bit_cast(float, mt.z);
    int dx = mt.w & 0xffff;
    int dy = (mt.w >> 16) & 0xffff;
    float w11 = wx * wy;
    float w01 = wx - w11;          // wx*(1-wy)
    float w10 = wy - w11;          // (1-wx)*wy
    float w00 = 1.f - wx - w10;    // (1-wx)*(1-wy)
    const char* pb = xbB + (mt.x + (oct << 4));
    const char* bb = stg + (tap & 1) * 8192;
#pragma unroll
    for (int half = 0; half < 2; ++half) {
      const char* pc = pb + (half << 6);
      uint4 q00 = *(const uint4*)(pc);
      uint4 q01 = *(const uint4*)(pc + dx);
      uint4 q10 = *(const uint4*)(pc + dy);
      uint4 q11 = *(const uint4*)(pc + dx + dy);
      unsigned av[4];
#pragma unroll
      for (int j = 0; j < 4; ++j) {
        unsigned u00 = ((const unsigned*)&q00)[j];
        unsigned u01 = ((const unsigned*)&q01)[j];
        unsigned u10 = ((const unsigned*)&q10)[j];
        unsigned u11 = ((const unsigned*)&q11)[j];
        float sl = blo(u00) * w00 + blo(u01) * w01 + blo(u10) * w10 + blo(u11) * w11;
        float sh = bhi(u00) * w00 + bhi(u01) * w01 + bhi(u10) * w10 + bhi(u11) * w11;
        av[j] = packbf(sl, sh);
      }
      bf16x8 a = __builtin_bit_cast(bf16x8, *(uint4*)av);
      const char* bh = bb + (half << 12) + lane * 16;
      bf16x8 b0 = *(const bf16x8*)(bh);
      bf16x8 b1 = *(const bf16x8*)(bh + 1024);
      bf16x8 b2 = *(const bf16x8*)(bh + 2048);
      bf16x8 b3 = *(const bf16x8*)(bh + 3072);
      acc0 = __builtin_amdgcn_mfma_f32_16x16x32_bf16(a, b0, acc0, 0, 0, 0);
      acc1 = __builtin_amdgcn_mfma_f32_16x16x32_bf16(a, b1, acc1, 0, 0, 0);
      acc2 = __builtin_amdgcn_mfma_f32_16x16x32_bf16(a, b2, acc2, 0, 0, 0);
      acc3 = __builtin_amdgcn_mfma_f32_16x16x32_bf16(a, b3, acc3, 0, 0, 0);
    }
    if (tap < 8) {
      *(uint4*)(stg + ((tap + 1) & 1) * 8192 + tid * 16) = n0;
      *(uint4*)(stg + ((tap + 1) & 1) * 8192 + 4096 + tid * 16) = n1;
    }
    __syncthreads();
  }

  // ---- P4: epilogue via LDS transpose (pitch 68), coalesced NCHW store.
  int prow0 = wv * 16 + (oct << 2);
#pragma unroll
  for (int r = 0; r < 4; ++r) {
    olds[(prow0 + r) * 68 + p     ] = acc0[r];
    olds[(prow0 + r) * 68 + p + 16] = acc1[r];
    olds[(prow0 + r) * 68 + p + 32] = acc2[r];
    olds[(prow0 + r) * 68 + p + 48] = acc3[r];
  }
  __syncthreads();
  float* ob = out + (size_t)n * COUT * 16384 + (size_t)h * 128 + w0;
  for (int i = tid; i < 4096; i += 256) {
    int co = i >> 6, px = i & 63;
    ob[(size_t)co * 16384 + px] = olds[px * 68 + co] + b_conv[co];
  }
}

// ---------------------------------------------------------------------------
extern "C" void kernel_launch(void* const* d_in, const int* in_sizes, int n_in,
                              void* d_out, int out_size, void* d_ws, size_t ws_size,
                              hipStream_t stream) {
  const float* x      = (const float*)d_in[0];
  const float* w_off  = (const float*)d_in[1];
  const float* b_off  = (const float*)d_in[2];
  const float* w_conv = (const float*)d_in[3];
  const float* b_conv = (const float*)d_in[4];
  float* out = (float*)d_out;

  char* ws = (char*)d_ws;
  __hip_bfloat16* xpT = (__hip_bfloat16*)ws;             // 17,305,600 B
  short* Bpack    = (short*)(ws + 17305600);             //     73,728 B
  short* wOffPack = (short*)(ws + 17305600 + 73728);     //     36,864 B

  k_pad_prep<<<dim3(8 * PH + 27), dim3(256), 0, stream>>>(x, w_off, w_conv,
                                                          xpT, Bpack, wOffPack);
  k_fused<<<dim3(2048), dim3(256), 0, stream>>>(xpT, Bpack, wOffPack, b_off, b_conv, out);
}

// Round 10
// 166.062 us; speedup vs baseline: 1.4409x; 1.0637x over previous
//
#include <hip/hip_runtime.h>
#include <hip/hip_bf16.h>

// Deformable conv v6: LDS neighborhood staging.
// v5 post-mortem: ~25-30us TCP lines + ~21us VALU + ~20us LDS + 18 barriers,
// serialized => 97us. v6: stage 7x72 pixel-records (64.5KB) per block into
// LDS once; all gathers (P3) and P1 A-reads hit LDS (XOR-swizzled, ~even
// bank slots); only 4 barriers/block; P3 tap loop barrier-free. B/wOff frags
// global-direct. Out-of-window offsets (|off|>=2, ~8sigma: never) fall back
// to per-tap global gather via LDS flag.
//
// ws layout (bytes):
//   [0)          xpT      bf16 [8][130][130][64] = 17,305,600
//   [17305600)   Bpack    bf16 [18][4][64][8]    =     73,728
//   [17379328)   wOffPack bf16 [18][2][64][8]    =     36,864

#define PH   130
#define CIN  64
#define COUT 64
#define WROWS 7
#define WCOLS 72            // 72 % 8 == 0  => swizzle key = col & 7
#define ROWB  (WCOLS * 128) // 9216 B per window row
#define WINB  (WROWS * ROWB)// 64512 B window

typedef __attribute__((ext_vector_type(8))) __bf16 bf16x8;
typedef __attribute__((ext_vector_type(4))) float  f32x4;

__device__ __forceinline__ short f2bf(float f) {
  return __builtin_bit_cast(short, __float2bfloat16(f));
}
__device__ __forceinline__ float blo(unsigned u) {
  return __builtin_bit_cast(float, u << 16);
}
__device__ __forceinline__ float bhi(unsigned u) {
  return __builtin_bit_cast(float, u & 0xffff0000u);
}
__device__ __forceinline__ unsigned packbf(float a, float b) {
  unsigned lo16 = (unsigned short)__builtin_bit_cast(unsigned short, __float2bfloat16(a));
  unsigned hi16 = (unsigned short)__builtin_bit_cast(unsigned short, __float2bfloat16(b));
  return lo16 | (hi16 << 16);
}

// ---------------- K1: pad+transpose (blocks <1040) and weight pack (rest) ---
__global__ __launch_bounds__(256) void k_pad_prep(
    const float* __restrict__ x, const float* __restrict__ w_off,
    const float* __restrict__ w_conv, __hip_bfloat16* __restrict__ xpT,
    short* __restrict__ Bpack, short* __restrict__ wOffPack) {
  __shared__ __hip_bfloat16 tile[128 * 64];  // [w][c], c XOR-swizzled by (w>>2)&7
  int bid = blockIdx.x;
  int tid = threadIdx.x;
  if (bid < 8 * PH) {
    int n = bid / PH;
    int y = bid % PH;
    bool interior = (y >= 1 && y <= 128);
    if (interior) {
      for (int i = tid; i < 2048; i += 256) {       // 64 ch x 32 float4
        int c  = i >> 5;
        int w4 = (i & 31) << 2;
        float4 v = *(const float4*)(x + (((size_t)(n * 64 + c) * 128) + (y - 1)) * 128 + w4);
        int sw = (i & 7) << 3;
        tile[(w4 + 0) * 64 + (c ^ sw)] = __float2bfloat16(v.x);
        tile[(w4 + 1) * 64 + (c ^ sw)] = __float2bfloat16(v.y);
        tile[(w4 + 2) * 64 + (c ^ sw)] = __float2bfloat16(v.z);
        tile[(w4 + 3) * 64 + (c ^ sw)] = __float2bfloat16(v.w);
      }
    }
    __syncthreads();
    __hip_bfloat16* dst = xpT + (size_t)(n * PH + y) * PH * CIN;
    bool zrow = (y == 0 || y == PH - 1);
    for (int i = tid; i < 1040; i += 256) {          // 130 px * 64 ch / 8
      int px = i >> 3;
      int c0 = (i & 7) << 3;
      uint4 v;
      if (zrow || px == 0 || px == PH - 1) {
        v = make_uint4(0u, 0u, 0u, 0u);
      } else {
        int pxi = px - 1;
        int c0s = c0 ^ (((pxi >> 2) & 7) << 3);
        v = *(const uint4*)&tile[pxi * 64 + c0s];
      }
      *(uint4*)(dst + (size_t)i * 8) = v;
    }
  } else {
    // weight pack into MFMA B-fragment order:
    // frag elem i, lane l, k-step kk: k = kk*32+(l>>4)*8+i, tap=k/64, ci=k%64,
    // co = nt*16+(l&15).
    int t = (bid - 8 * PH) * 256 + tid;
    if (t < 18 * 4 * 64) {
      int lane = t & 63;
      int nt   = (t >> 6) & 3;
      int kk   = t >> 8;
      int co   = nt * 16 + (lane & 15);
      int kbase = kk * 32 + ((lane >> 4) << 3);
      short v[8];
#pragma unroll
      for (int i = 0; i < 8; ++i) {
        int k = kbase + i;
        v[i] = f2bf(w_conv[(size_t)(co * 64 + (k & 63)) * 9 + (k >> 6)]);
      }
      *(uint4*)(Bpack + (size_t)t * 8) = *(const uint4*)v;
    }
    int u = t - 18 * 4 * 64;
    if (u >= 0 && u < 18 * 2 * 64) {
      int lane = u & 63;
      int nt   = (u >> 6) & 1;
      int kk   = u >> 7;
      int co   = nt * 16 + (lane & 15);
      int kbase = kk * 32 + ((lane >> 4) << 3);
      short v[8];
#pragma unroll
      for (int i = 0; i < 8; ++i) {
        int k = kbase + i;
        v[i] = (co < 18) ? f2bf(w_off[(size_t)(co * 64 + (k & 63)) * 9 + (k >> 6)]) : (short)0;
      }
      *(uint4*)(wOffPack + (size_t)u * 8) = *(const uint4*)v;
    }
  }
}

// ---------------- K2: fused, window-staged --------------------------------
// LDS map (78,912 B): win [0,64512); offsLds f32[64][20] [64512,69632);
// metaLds int4[576] [69632,78848); tf int[9] [78848,..); olds reuses [0,17408).
__global__ __launch_bounds__(256, 2) void k_fused(
    const __hip_bfloat16* __restrict__ xpT, const short* __restrict__ Bpack,
    const short* __restrict__ wOffPack, const float* __restrict__ b_off,
    const float* __restrict__ b_conv, float* __restrict__ out) {
  __shared__ __attribute__((aligned(16))) char shraw[78912];
  char*  win     = shraw;
  float* offsLds = (float*)(shraw + WINB);
  int4*  metaLds = (int4*)(shraw + WINB + 5120);
  int*   tf      = (int*)(shraw + WINB + 5120 + 9216);
  float* olds    = (float*)shraw;

  int bid = blockIdx.x;                      // 8*128*2
  int wh  = bid & 1;
  int h   = (bid >> 1) & 127;
  int n   = bid >> 8;
  int w0  = wh << 6;
  int tid = threadIdx.x, wv = tid >> 6, lane = tid & 63;
  int p = lane & 15, oct = lane >> 4;
  const char* xbB = (const char*)(xpT + (size_t)n * PH * PH * CIN);

  // ---- Stage window: rows h-2..h+4, cols w0-2..w0+69 (504 records x 128B).
  if (tid < 9) tf[tid] = 0;
  for (int i = tid; i < 4032; i += 256) {    // 504 recs * 8 chunks
    int rec = i >> 3, chunk = i & 7;
    int r = rec / WCOLS, c = rec - r * WCOLS;
    int wrow = h - 2 + r, wcol = w0 - 2 + c;
    if ((unsigned)wrow <= 129u && (unsigned)wcol <= 129u) {
      uint4 v = *(const uint4*)(xbB + (size_t)(wrow * 130 + wcol) * 128 + chunk * 16);
      *(uint4*)(win + rec * 128 + ((chunk * 16) ^ ((c & 7) << 4))) = v;
    }
  }
  __syncthreads();

  // ---- P1: offset conv. A from window (LDS), B from global wOffPack.
  {
    f32x4 ao0 = {0.f, 0.f, 0.f, 0.f}, ao1 = ao0;
    const bf16x8* Wo = (const bf16x8*)wOffPack;
    int colbase = 2 + wv * 16 + p;
#pragma unroll
    for (int kk = 0; kk < 18; ++kk) {
      int tap = kk >> 1;
      int ky = tap / 3, kx = tap - (tap / 3) * 3;
      int sub = kk & 1;
      int col = colbase + kx;
      int addr = (2 + ky) * ROWB + col * 128 + ((oct * 16 + sub * 64) ^ ((col & 7) << 4));
      bf16x8 a  = *(const bf16x8*)(win + addr);
      bf16x8 b0 = Wo[(kk * 2 + 0) * 64 + lane];
      bf16x8 b1 = Wo[(kk * 2 + 1) * 64 + lane];
      ao0 = __builtin_amdgcn_mfma_f32_16x16x32_bf16(a, b0, ao0, 0, 0, 0);
      ao1 = __builtin_amdgcn_mfma_f32_16x16x32_bf16(a, b1, ao1, 0, 0, 0);
    }
    int co = lane & 15;
    float bo0 = b_off[co];
#pragma unroll
    for (int r = 0; r < 4; ++r)
      offsLds[(wv * 16 + oct * 4 + r) * 20 + co] = ao0[r] + bo0;
    if (co < 2) {
      float bo1 = b_off[16 + co];
#pragma unroll
      for (int r = 0; r < 4; ++r)
        offsLds[(wv * 16 + oct * 4 + r) * 20 + 16 + co] = ao1[r] + bo1;
    }
  }
  __syncthreads();

  // ---- P2: sampling metadata + per-tap window flags.
  for (int t = tid; t < 576; t += 256) {
    int pix = t / 9, tap = t - pix * 9;
    int ky = tap / 3, kx = tap - (tap / 3) * 3;
    float cx = offsLds[pix * 20 + tap]     + (float)(w0 + pix + kx);
    float cy = offsLds[pix * 20 + 9 + tap] + (float)(h + ky);
    cx = fminf(fmaxf(cx, 0.f), 129.f);
    cy = fminf(fmaxf(cy, 0.f), 129.f);
    float x0f = floorf(cx), y0f = floorf(cy);
    int x0i = (int)x0f, y0i = (int)y0f;
    float wx = cx - x0f, wy = cy - y0f;
    int x1i = min(x0i + 1, 129), y1i = min(y0i + 1, 129);
    int x0r = x0i - w0 + 2, y0r = y0i - h + 2;
    int x1r = x1i - w0 + 2, y1r = y1i - h + 2;
    bool inw = (x0r >= 0) && (y0r >= 0) && (x1r <= WCOLS - 1) && (y1r <= WROWS - 1);
    if (!inw) atomicOr(&tf[tap], 1);
    int dxr = x1i - x0i, dyr = y1i - y0i;            // 0/1
    int rec00 = (y0r * WCOLS + x0r) & 511;
    metaLds[t] = make_int4((y0i * 130 + x0i) << 7, __builtin_bit_cast(int, wx),
                           __builtin_bit_cast(int, wy),
                           rec00 | (dxr << 9) | (dyr << 10));
  }
  __syncthreads();

  // ---- P3: main conv. Gathers from LDS window (or rare global fallback).
  f32x4 acc0 = {0.f, 0.f, 0.f, 0.f}, acc1 = acc0, acc2 = acc0, acc3 = acc0;
  const bf16x8* Bp = (const bf16x8*)Bpack;
  int mbase = (wv * 16 + p) * 9;
  int innerQ = oct * 16;
  for (int tap = 0; tap < 9; ++tap) {
    int tfv = tf[tap];
    int4 mt = metaLds[mbase + tap];
    float wx = __builtin_bit_cast(float, mt.y);
    float wy = __builtin_bit_cast(float, mt.z);
    float w11 = wx * wy;
    float w01 = wx - w11;
    float w10 = wy - w11;
    float w00 = 1.f - wx - w10;
    int wrd = mt.w;
    int dxr = (wrd >> 9) & 1, dyr = (wrd >> 10) & 1;
    int a00 = 0, a01 = 0, a10 = 0, a11 = 0;
    const char* pb = nullptr;
    int dx = 0, dy = 0;
    if (tfv == 0) {
      int r00 = wrd & 511;
      int r01 = r00 + dxr, r10 = r00 + WCOLS * dyr, r11 = r10 + dxr;
      a00 = r00 * 128 + (innerQ ^ ((r00 & 7) << 4));
      a01 = r01 * 128 + (innerQ ^ ((r01 & 7) << 4));
      a10 = r10 * 128 + (innerQ ^ ((r10 & 7) << 4));
      a11 = r11 * 128 + (innerQ ^ ((r11 & 7) << 4));
    } else {
      pb = xbB + mt.x + (oct << 4);
      dx = dxr << 7;
      dy = dyr * 16640;
    }
#pragma unroll
    for (int half = 0; half < 2; ++half) {
      uint4 q00, q01, q10, q11;
      if (tfv == 0) {
        int hx = half << 6;                  // bit6 outside rec field, XOR-safe
        q00 = *(const uint4*)(win + (a00 ^ hx));
        q01 = *(const uint4*)(win + (a01 ^ hx));
        q10 = *(const uint4*)(win + (a10 ^ hx));
        q11 = *(const uint4*)(win + (a11 ^ hx));
      } else {
        const char* pc = pb + (half << 6);
        q00 = *(const uint4*)(pc);
        q01 = *(const uint4*)(pc + dx);
        q10 = *(const uint4*)(pc + dy);
        q11 = *(const uint4*)(pc + dx + dy);
      }
      unsigned av[4];
#pragma unroll
      for (int j = 0; j < 4; ++j) {
        unsigned u00 = ((const unsigned*)&q00)[j];
        unsigned u01 = ((const unsigned*)&q01)[j];
        unsigned u10 = ((const unsigned*)&q10)[j];
        unsigned u11 = ((const unsigned*)&q11)[j];
        float sl = blo(u00) * w00 + blo(u01) * w01 + blo(u10) * w10 + blo(u11) * w11;
        float sh = bhi(u00) * w00 + bhi(u01) * w01 + bhi(u10) * w10 + bhi(u11) * w11;
        av[j] = packbf(sl, sh);
      }
      bf16x8 a = __builtin_bit_cast(bf16x8, *(uint4*)av);
      int kk = tap * 2 + half;
      bf16x8 b0 = Bp[(kk * 4 + 0) * 64 + lane];
      bf16x8 b1 = Bp[(kk * 4 + 1) * 64 + lane];
      bf16x8 b2 = Bp[(kk * 4 + 2) * 64 + lane];
      bf16x8 b3 = Bp[(kk * 4 + 3) * 64 + lane];
      acc0 = __builtin_amdgcn_mfma_f32_16x16x32_bf16(a, b0, acc0, 0, 0, 0);
      acc1 = __builtin_amdgcn_mfma_f32_16x16x32_bf16(a, b1, acc1, 0, 0, 0);
      acc2 = __builtin_amdgcn_mfma_f32_16x16x32_bf16(a, b2, acc2, 0, 0, 0);
      acc3 = __builtin_amdgcn_mfma_f32_16x16x32_bf16(a, b3, acc3, 0, 0, 0);
    }
  }
  __syncthreads();

  // ---- P4: epilogue via LDS transpose (pitch 68), coalesced NCHW store.
  int prow0 = wv * 16 + (oct << 2);
#pragma unroll
  for (int r = 0; r < 4; ++r) {
    olds[(prow0 + r) * 68 + p     ] = acc0[r];
    olds[(prow0 + r) * 68 + p + 16] = acc1[r];
    olds[(prow0 + r) * 68 + p + 32] = acc2[r];
    olds[(prow0 + r) * 68 + p + 48] = acc3[r];
  }
  __syncthreads();
  float* ob = out + (size_t)n * COUT * 16384 + (size_t)h * 128 + w0;
  for (int i = tid; i < 4096; i += 256) {
    int co = i >> 6, px = i & 63;
    ob[(size_t)co * 16384 + px] = olds[px * 68 + co] + b_conv[co];
  }
}

// ---------------------------------------------------------------------------
extern "C" void kernel_launch(void* const* d_in, const int* in_sizes, int n_in,
                              void* d_out, int out_size, void* d_ws, size_t ws_size,
                              hipStream_t stream) {
  const float* x      = (const float*)d_in[0];
  const float* w_off  = (const float*)d_in[1];
  const float* b_off  = (const float*)d_in[2];
  const float* w_conv = (const float*)d_in[3];
  const float* b_conv = (const float*)d_in[4];
  float* out = (float*)d_out;

  char* ws = (char*)d_ws;
  __hip_bfloat16* xpT = (__hip_bfloat16*)ws;             // 17,305,600 B
  short* Bpack    = (short*)(ws + 17305600);             //     73,728 B
  short* wOffPack = (short*)(ws + 17305600 + 73728);     //     36,864 B

  k_pad_prep<<<dim3(8 * PH + 27), dim3(256), 0, stream>>>(x, w_off, w_conv,
                                                          xpT, Bpack, wOffPack);
  k_fused<<<dim3(2048), dim3(256), 0, stream>>>(xpT, Bpack, wOffPack, b_off, b_conv, out);
}

// Round 11
// 161.920 us; speedup vs baseline: 1.4778x; 1.0256x over previous
//
#include <hip/hip_runtime.h>
#include <hip/hip_bf16.h>

// Deformable conv v7: ILP restructure of P3.
// v6 post-mortem: 82us, VALU 37%, occupancy 19.6% (LDS-capped, by design) =>
// ~45us of per-tap dependency stall at 2 waves/SIMD. The runtime tf[tap]
// branch inside the tap loop blocked unroll/cross-tap pipelining. v7:
//  (1) tf -> one bitmask, read once; block-uniform branch: fb==0 (offsets are
//      0.24-sigma vs 8-sigma window guard => always) runs a fully-unrolled
//      branch-free 9-tap P3 (compiler hoists meta reads, issues ds_reads
//      taps ahead); fb!=0 runs the general loop (any-input correctness).
//  (2) f32x2 packed lerp (v_pk_fma_f32): halves lerp VALU ops.
//
// ws layout (bytes):
//   [0)          xpT      bf16 [8][130][130][64] = 17,305,600
//   [17305600)   Bpack    bf16 [18][4][64][8]    =     73,728
//   [17379328)   wOffPack bf16 [18][2][64][8]    =     36,864

#define PH   130
#define CIN  64
#define COUT 64
#define WROWS 7
#define WCOLS 72            // 72 % 8 == 0  => swizzle key = col & 7
#define ROWB  (WCOLS * 128) // 9216 B per window row
#define WINB  (WROWS * ROWB)// 64512 B window

typedef __attribute__((ext_vector_type(8))) __bf16 bf16x8;
typedef __attribute__((ext_vector_type(4))) float  f32x4;
typedef __attribute__((ext_vector_type(2))) float  f32x2;

__device__ __forceinline__ short f2bf(float f) {
  return __builtin_bit_cast(short, __float2bfloat16(f));
}
__device__ __forceinline__ unsigned packbf(float a, float b) {
  unsigned lo16 = (unsigned short)__builtin_bit_cast(unsigned short, __float2bfloat16(a));
  unsigned hi16 = (unsigned short)__builtin_bit_cast(unsigned short, __float2bfloat16(b));
  return lo16 | (hi16 << 16);
}
__device__ __forceinline__ f32x2 bf2x(unsigned u) {
  f32x2 r;
  r.x = __builtin_bit_cast(float, u << 16);
  r.y = __builtin_bit_cast(float, u & 0xffff0000u);
  return r;
}
// 8-channel bilinear lerp on packed bf16 quads -> bf16x8 MFMA A-fragment.
__device__ __forceinline__ bf16x8 lerp8(uint4 q00, uint4 q01, uint4 q10, uint4 q11,
                                        float w00, float w01, float w10, float w11) {
  unsigned av[4];
#pragma unroll
  for (int j = 0; j < 4; ++j) {
    f32x2 s = bf2x(((const unsigned*)&q00)[j]) * w00;
    s += bf2x(((const unsigned*)&q01)[j]) * w01;
    s += bf2x(((const unsigned*)&q10)[j]) * w10;
    s += bf2x(((const unsigned*)&q11)[j]) * w11;
    av[j] = packbf(s.x, s.y);
  }
  return __builtin_bit_cast(bf16x8, *(const uint4*)av);
}

// ---------------- K1: pad+transpose (blocks <1040) and weight pack (rest) ---
__global__ __launch_bounds__(256) void k_pad_prep(
    const float* __restrict__ x, const float* __restrict__ w_off,
    const float* __restrict__ w_conv, __hip_bfloat16* __restrict__ xpT,
    short* __restrict__ Bpack, short* __restrict__ wOffPack) {
  __shared__ __hip_bfloat16 tile[128 * 64];  // [w][c], c XOR-swizzled by (w>>2)&7
  int bid = blockIdx.x;
  int tid = threadIdx.x;
  if (bid < 8 * PH) {
    int n = bid / PH;
    int y = bid % PH;
    bool interior = (y >= 1 && y <= 128);
    if (interior) {
      for (int i = tid; i < 2048; i += 256) {       // 64 ch x 32 float4
        int c  = i >> 5;
        int w4 = (i & 31) << 2;
        float4 v = *(const float4*)(x + (((size_t)(n * 64 + c) * 128) + (y - 1)) * 128 + w4);
        int sw = (i & 7) << 3;
        tile[(w4 + 0) * 64 + (c ^ sw)] = __float2bfloat16(v.x);
        tile[(w4 + 1) * 64 + (c ^ sw)] = __float2bfloat16(v.y);
        tile[(w4 + 2) * 64 + (c ^ sw)] = __float2bfloat16(v.z);
        tile[(w4 + 3) * 64 + (c ^ sw)] = __float2bfloat16(v.w);
      }
    }
    __syncthreads();
    __hip_bfloat16* dst = xpT + (size_t)(n * PH + y) * PH * CIN;
    bool zrow = (y == 0 || y == PH - 1);
    for (int i = tid; i < 1040; i += 256) {          // 130 px * 64 ch / 8
      int px = i >> 3;
      int c0 = (i & 7) << 3;
      uint4 v;
      if (zrow || px == 0 || px == PH - 1) {
        v = make_uint4(0u, 0u, 0u, 0u);
      } else {
        int pxi = px - 1;
        int c0s = c0 ^ (((pxi >> 2) & 7) << 3);
        v = *(const uint4*)&tile[pxi * 64 + c0s];
      }
      *(uint4*)(dst + (size_t)i * 8) = v;
    }
  } else {
    // weight pack into MFMA B-fragment order:
    // frag elem i, lane l, k-step kk: k = kk*32+(l>>4)*8+i, tap=k/64, ci=k%64,
    // co = nt*16+(l&15).
    int t = (bid - 8 * PH) * 256 + tid;
    if (t < 18 * 4 * 64) {
      int lane = t & 63;
      int nt   = (t >> 6) & 3;
      int kk   = t >> 8;
      int co   = nt * 16 + (lane & 15);
      int kbase = kk * 32 + ((lane >> 4) << 3);
      short v[8];
#pragma unroll
      for (int i = 0; i < 8; ++i) {
        int k = kbase + i;
        v[i] = f2bf(w_conv[(size_t)(co * 64 + (k & 63)) * 9 + (k >> 6)]);
      }
      *(uint4*)(Bpack + (size_t)t * 8) = *(const uint4*)v;
    }
    int u = t - 18 * 4 * 64;
    if (u >= 0 && u < 18 * 2 * 64) {
      int lane = u & 63;
      int nt   = (u >> 6) & 1;
      int kk   = u >> 7;
      int co   = nt * 16 + (lane & 15);
      int kbase = kk * 32 + ((lane >> 4) << 3);
      short v[8];
#pragma unroll
      for (int i = 0; i < 8; ++i) {
        int k = kbase + i;
        v[i] = (co < 18) ? f2bf(w_off[(size_t)(co * 64 + (k & 63)) * 9 + (k >> 6)]) : (short)0;
      }
      *(uint4*)(wOffPack + (size_t)u * 8) = *(const uint4*)v;
    }
  }
}

// ---------------- K2: fused, window-staged --------------------------------
// LDS map (78,912 B): win [0,64512); offsLds f32[64][20] [64512,69632);
// metaLds int4[576] [69632,78848); tf int [78848,..); olds reuses [0,17408).
__global__ __launch_bounds__(256, 2) void k_fused(
    const __hip_bfloat16* __restrict__ xpT, const short* __restrict__ Bpack,
    const short* __restrict__ wOffPack, const float* __restrict__ b_off,
    const float* __restrict__ b_conv, float* __restrict__ out) {
  __shared__ __attribute__((aligned(16))) char shraw[78912];
  char*  win     = shraw;
  float* offsLds = (float*)(shraw + WINB);
  int4*  metaLds = (int4*)(shraw + WINB + 5120);
  int*   tf      = (int*)(shraw + WINB + 5120 + 9216);
  float* olds    = (float*)shraw;

  int bid = blockIdx.x;                      // 8*128*2
  int wh  = bid & 1;
  int h   = (bid >> 1) & 127;
  int n   = bid >> 8;
  int w0  = wh << 6;
  int tid = threadIdx.x, wv = tid >> 6, lane = tid & 63;
  int p = lane & 15, oct = lane >> 4;
  const char* xbB = (const char*)(xpT + (size_t)n * PH * PH * CIN);

  // ---- Stage window: rows h-2..h+4, cols w0-2..w0+69 (504 records x 128B).
  if (tid == 0) tf[0] = 0;
  for (int i = tid; i < 4032; i += 256) {    // 504 recs * 8 chunks
    int rec = i >> 3, chunk = i & 7;
    int r = rec / WCOLS, c = rec - r * WCOLS;
    int wrow = h - 2 + r, wcol = w0 - 2 + c;
    if ((unsigned)wrow <= 129u && (unsigned)wcol <= 129u) {
      uint4 v = *(const uint4*)(xbB + (size_t)(wrow * 130 + wcol) * 128 + chunk * 16);
      *(uint4*)(win + rec * 128 + ((chunk * 16) ^ ((c & 7) << 4))) = v;
    }
  }
  __syncthreads();

  // ---- P1: offset conv. A from window (LDS), B from global wOffPack.
  {
    f32x4 ao0 = {0.f, 0.f, 0.f, 0.f}, ao1 = ao0;
    const bf16x8* Wo = (const bf16x8*)wOffPack;
    int colbase = 2 + wv * 16 + p;
#pragma unroll
    for (int kk = 0; kk < 18; ++kk) {
      int tap = kk >> 1;
      int ky = tap / 3, kx = tap - (tap / 3) * 3;
      int sub = kk & 1;
      int col = colbase + kx;
      int addr = (2 + ky) * ROWB + col * 128 + ((oct * 16 + sub * 64) ^ ((col & 7) << 4));
      bf16x8 a  = *(const bf16x8*)(win + addr);
      bf16x8 b0 = Wo[(kk * 2 + 0) * 64 + lane];
      bf16x8 b1 = Wo[(kk * 2 + 1) * 64 + lane];
      ao0 = __builtin_amdgcn_mfma_f32_16x16x32_bf16(a, b0, ao0, 0, 0, 0);
      ao1 = __builtin_amdgcn_mfma_f32_16x16x32_bf16(a, b1, ao1, 0, 0, 0);
    }
    int co = lane & 15;
    float bo0 = b_off[co];
#pragma unroll
    for (int r = 0; r < 4; ++r)
      offsLds[(wv * 16 + oct * 4 + r) * 20 + co] = ao0[r] + bo0;
    if (co < 2) {
      float bo1 = b_off[16 + co];
#pragma unroll
      for (int r = 0; r < 4; ++r)
        offsLds[(wv * 16 + oct * 4 + r) * 20 + 16 + co] = ao1[r] + bo1;
    }
  }
  __syncthreads();

  // ---- P2: sampling metadata + window-miss bitmask.
  for (int t = tid; t < 576; t += 256) {
    int pix = t / 9, tap = t - pix * 9;
    int ky = tap / 3, kx = tap - (tap / 3) * 3;
    float cx = offsLds[pix * 20 + tap]     + (float)(w0 + pix + kx);
    float cy = offsLds[pix * 20 + 9 + tap] + (float)(h + ky);
    cx = fminf(fmaxf(cx, 0.f), 129.f);
    cy = fminf(fmaxf(cy, 0.f), 129.f);
    float x0f = floorf(cx), y0f = floorf(cy);
    int x0i = (int)x0f, y0i = (int)y0f;
    float wx = cx - x0f, wy = cy - y0f;
    int x1i = min(x0i + 1, 129), y1i = min(y0i + 1, 129);
    int x0r = x0i - w0 + 2, y0r = y0i - h + 2;
    int x1r = x1i - w0 + 2, y1r = y1i - h + 2;
    bool inw = (x0r >= 0) && (y0r >= 0) && (x1r <= WCOLS - 1) && (y1r <= WROWS - 1);
    if (!inw) atomicOr(&tf[0], 1 << tap);
    int dxr = x1i - x0i, dyr = y1i - y0i;            // 0/1
    int rec00 = (y0r * WCOLS + x0r) & 511;
    metaLds[t] = make_int4((y0i * 130 + x0i) << 7, __builtin_bit_cast(int, wx),
                           __builtin_bit_cast(int, wy),
                           rec00 | (dxr << 9) | (dyr << 10));
  }
  __syncthreads();

  // ---- P3: main conv.
  f32x4 acc0 = {0.f, 0.f, 0.f, 0.f}, acc1 = acc0, acc2 = acc0, acc3 = acc0;
  const bf16x8* Bp = (const bf16x8*)Bpack;
  int mbase = (wv * 16 + p) * 9;
  int innerQ = oct * 16;
  int fb = tf[0];                            // block-uniform
  if (__builtin_expect(fb == 0, 1)) {
    // FAST: all samples in window; branch-free, fully unrolled =>
    // compiler pipelines ds_reads across taps.
#pragma unroll
    for (int tap = 0; tap < 9; ++tap) {
      int4 mt = metaLds[mbase + tap];
      float wx = __builtin_bit_cast(float, mt.y);
      float wy = __builtin_bit_cast(float, mt.z);
      float w11 = wx * wy;
      float w01 = wx - w11;
      float w10 = wy - w11;
      float w00 = 1.f - wx - w10;
      int wrd = mt.w;
      int dxr = (wrd >> 9) & 1, dyr = (wrd >> 10) & 1;
      int r00 = wrd & 511;
      int r01 = r00 + dxr, r10 = r00 + WCOLS * dyr, r11 = r10 + dxr;
      int a00 = r00 * 128 + (innerQ ^ ((r00 & 7) << 4));
      int a01 = r01 * 128 + (innerQ ^ ((r01 & 7) << 4));
      int a10 = r10 * 128 + (innerQ ^ ((r10 & 7) << 4));
      int a11 = r11 * 128 + (innerQ ^ ((r11 & 7) << 4));
#pragma unroll
      for (int half = 0; half < 2; ++half) {
        int hx = half << 6;                  // bit6 outside rec field, XOR-safe
        uint4 q00 = *(const uint4*)(win + (a00 ^ hx));
        uint4 q01 = *(const uint4*)(win + (a01 ^ hx));
        uint4 q10 = *(const uint4*)(win + (a10 ^ hx));
        uint4 q11 = *(const uint4*)(win + (a11 ^ hx));
        bf16x8 a = lerp8(q00, q01, q10, q11, w00, w01, w10, w11);
        int kk = tap * 2 + half;
        bf16x8 b0 = Bp[(kk * 4 + 0) * 64 + lane];
        bf16x8 b1 = Bp[(kk * 4 + 1) * 64 + lane];
        bf16x8 b2 = Bp[(kk * 4 + 2) * 64 + lane];
        bf16x8 b3 = Bp[(kk * 4 + 3) * 64 + lane];
        acc0 = __builtin_amdgcn_mfma_f32_16x16x32_bf16(a, b0, acc0, 0, 0, 0);
        acc1 = __builtin_amdgcn_mfma_f32_16x16x32_bf16(a, b1, acc1, 0, 0, 0);
        acc2 = __builtin_amdgcn_mfma_f32_16x16x32_bf16(a, b2, acc2, 0, 0, 0);
        acc3 = __builtin_amdgcn_mfma_f32_16x16x32_bf16(a, b3, acc3, 0, 0, 0);
      }
    }
  } else {
    // SLOW: general path (any offsets). Runtime loop, per-tap uniform branch.
    for (int tap = 0; tap < 9; ++tap) {
      int tfv = (fb >> tap) & 1;
      int4 mt = metaLds[mbase + tap];
      float wx = __builtin_bit_cast(float, mt.y);
      float wy = __builtin_bit_cast(float, mt.z);
      float w11 = wx * wy;
      float w01 = wx - w11;
      float w10 = wy - w11;
      float w00 = 1.f - wx - w10;
      int wrd = mt.w;
      int dxr = (wrd >> 9) & 1, dyr = (wrd >> 10) & 1;
      int a00 = 0, a01 = 0, a10 = 0, a11 = 0;
      const char* pb = nullptr;
      int dx = 0, dy = 0;
      if (tfv == 0) {
        int r00 = wrd & 511;
        int r01 = r00 + dxr, r10 = r00 + WCOLS * dyr, r11 = r10 + dxr;
        a00 = r00 * 128 + (innerQ ^ ((r00 & 7) << 4));
        a01 = r01 * 128 + (innerQ ^ ((r01 & 7) << 4));
        a10 = r10 * 128 + (innerQ ^ ((r10 & 7) << 4));
        a11 = r11 * 128 + (innerQ ^ ((r11 & 7) << 4));
      } else {
        pb = xbB + mt.x + (oct << 4);
        dx = dxr << 7;
        dy = dyr * 16640;
      }
#pragma unroll
      for (int half = 0; half < 2; ++half) {
        uint4 q00, q01, q10, q11;
        if (tfv == 0) {
          int hx = half << 6;
          q00 = *(const uint4*)(win + (a00 ^ hx));
          q01 = *(const uint4*)(win + (a01 ^ hx));
          q10 = *(const uint4*)(win + (a10 ^ hx));
          q11 = *(const uint4*)(win + (a11 ^ hx));
        } else {
          const char* pc = pb + (half << 6);
          q00 = *(const uint4*)(pc);
          q01 = *(const uint4*)(pc + dx);
          q10 = *(const uint4*)(pc + dy);
          q11 = *(const uint4*)(pc + dx + dy);
        }
        bf16x8 a = lerp8(q00, q01, q10, q11, w00, w01, w10, w11);
        int kk = tap * 2 + half;
        bf16x8 b0 = Bp[(kk * 4 + 0) * 64 + lane];
        bf16x8 b1 = Bp[(kk * 4 + 1) * 64 + lane];
        bf16x8 b2 = Bp[(kk * 4 + 2) * 64 + lane];
        bf16x8 b3 = Bp[(kk * 4 + 3) * 64 + lane];
        acc0 = __builtin_amdgcn_mfma_f32_16x16x32_bf16(a, b0, acc0, 0, 0, 0);
        acc1 = __builtin_amdgcn_mfma_f32_16x16x32_bf16(a, b1, acc1, 0, 0, 0);
        acc2 = __builtin_amdgcn_mfma_f32_16x16x32_bf16(a, b2, acc2, 0, 0, 0);
        acc3 = __builtin_amdgcn_mfma_f32_16x16x32_bf16(a, b3, acc3, 0, 0, 0);
      }
    }
  }
  __syncthreads();

  // ---- P4: epilogue via LDS transpose (pitch 68), coalesced NCHW store.
  int prow0 = wv * 16 + (oct << 2);
#pragma unroll
  for (int r = 0; r < 4; ++r) {
    olds[(prow0 + r) * 68 + p     ] = acc0[r];
    olds[(prow0 + r) * 68 + p + 16] = acc1[r];
    olds[(prow0 + r) * 68 + p + 32] = acc2[r];
    olds[(prow0 + r) * 68 + p + 48] = acc3[r];
  }
  __syncthreads();
  float* ob = out + (size_t)n * COUT * 16384 + (size_t)h * 128 + w0;
  for (int i = tid; i < 4096; i += 256) {
    int co = i >> 6, px = i & 63;
    ob[(size_t)co * 16384 + px] = olds[px * 68 + co] + b_conv[co];
  }
}

// ---------------------------------------------------------------------------
extern "C" void kernel_launch(void* const* d_in, const int* in_sizes, int n_in,
                              void* d_out, int out_size, void* d_ws, size_t ws_size,
                              hipStream_t stream) {
  const float* x      = (const float*)d_in[0];
  const float* w_off  = (const float*)d_in[1];
  const float* b_off  = (const float*)d_in[2];
  const float* w_conv = (const float*)d_in[3];
  const float* b_conv = (const float*)d_in[4];
  float* out = (float*)d_out;

  char* ws = (char*)d_ws;
  __hip_bfloat16* xpT = (__hip_bfloat16*)ws;             // 17,305,600 B
  short* Bpack    = (short*)(ws + 17305600);             //     73,728 B
  short* wOffPack = (short*)(ws + 17305600 + 73728);     //     36,864 B

  k_pad_prep<<<dim3(8 * PH + 27), dim3(256), 0, stream>>>(x, w_off, w_conv,
                                                          xpT, Bpack, wOffPack);
  k_fused<<<dim3(2048), dim3(256), 0, stream>>>(xpT, Bpack, wOffPack, b_off, b_conv, out);
}

// Round 12
// 147.212 us; speedup vs baseline: 1.6254x; 1.0999x over previous
//
#include <hip/hip_runtime.h>
#include <hip/hip_bf16.h>

// Deformable conv v8: 3 blocks/CU via LDS diet; v6 P3 structure restored.
// v7 post-mortem: full unroll +22us stall (register-reuse serialization at
// 88 VGPR); VALU cycles constant ~30us across v6/v7; packed lerp = no-op.
// => stall only attackable via TLP. v8 shrinks LDS 79.4KB -> 53.3KB:
//   - window 7 -> 5 rows (h-1..h+3; |off|<1 at 4-sigma; fallback covers rest)
//   - offsLds fp32 -> bf16
//   - metaLds 16B -> 8B (rec|dxr|dyr|x0i|y0i ; wx,wy fp16)
// -> 3 blocks/CU (was 2), launch_bounds(256,3). P3 = v6 runtime loop,
// pinned #pragma unroll 1 (v7 showed unroll regresses).
//
// ws layout (bytes):
//   [0)          xpT      bf16 [8][130][130][64] = 17,305,600
//   [17305600)   Bpack    bf16 [18][4][64][8]    =     73,728
//   [17379328)   wOffPack bf16 [18][2][64][8]    =     36,864

#define PH   130
#define CIN  64
#define COUT 64
#define WROWS 5
#define WCOLS 72            // 72 % 8 == 0 => rec&7 == col&7 (swizzle key)
#define ROWB  (WCOLS * 128) // 9216 B per window row
#define WINB  (WROWS * ROWB)// 46080 B window

typedef __attribute__((ext_vector_type(8))) __bf16 bf16x8;
typedef __attribute__((ext_vector_type(4))) float  f32x4;

__device__ __forceinline__ short f2bf(float f) {
  return __builtin_bit_cast(short, __float2bfloat16(f));
}
__device__ __forceinline__ float blo(unsigned u) {
  return __builtin_bit_cast(float, u << 16);
}
__device__ __forceinline__ float bhi(unsigned u) {
  return __builtin_bit_cast(float, u & 0xffff0000u);
}
__device__ __forceinline__ unsigned packbf(float a, float b) {
  unsigned lo16 = (unsigned short)__builtin_bit_cast(unsigned short, __float2bfloat16(a));
  unsigned hi16 = (unsigned short)__builtin_bit_cast(unsigned short, __float2bfloat16(b));
  return lo16 | (hi16 << 16);
}
__device__ __forceinline__ unsigned short f2h(float f) {
  return __builtin_bit_cast(unsigned short, (_Float16)f);
}
__device__ __forceinline__ float h2f(unsigned short h) {
  return (float)__builtin_bit_cast(_Float16, h);
}

// ---------------- K1: pad+transpose (blocks <1040) and weight pack (rest) ---
__global__ __launch_bounds__(256) void k_pad_prep(
    const float* __restrict__ x, const float* __restrict__ w_off,
    const float* __restrict__ w_conv, __hip_bfloat16* __restrict__ xpT,
    short* __restrict__ Bpack, short* __restrict__ wOffPack) {
  __shared__ __hip_bfloat16 tile[128 * 64];  // [w][c], c XOR-swizzled by (w>>2)&7
  int bid = blockIdx.x;
  int tid = threadIdx.x;
  if (bid < 8 * PH) {
    int n = bid / PH;
    int y = bid % PH;
    bool interior = (y >= 1 && y <= 128);
    if (interior) {
      for (int i = tid; i < 2048; i += 256) {       // 64 ch x 32 float4
        int c  = i >> 5;
        int w4 = (i & 31) << 2;
        float4 v = *(const float4*)(x + (((size_t)(n * 64 + c) * 128) + (y - 1)) * 128 + w4);
        int sw = (i & 7) << 3;
        tile[(w4 + 0) * 64 + (c ^ sw)] = __float2bfloat16(v.x);
        tile[(w4 + 1) * 64 + (c ^ sw)] = __float2bfloat16(v.y);
        tile[(w4 + 2) * 64 + (c ^ sw)] = __float2bfloat16(v.z);
        tile[(w4 + 3) * 64 + (c ^ sw)] = __float2bfloat16(v.w);
      }
    }
    __syncthreads();
    __hip_bfloat16* dst = xpT + (size_t)(n * PH + y) * PH * CIN;
    bool zrow = (y == 0 || y == PH - 1);
    for (int i = tid; i < 1040; i += 256) {          // 130 px * 64 ch / 8
      int px = i >> 3;
      int c0 = (i & 7) << 3;
      uint4 v;
      if (zrow || px == 0 || px == PH - 1) {
        v = make_uint4(0u, 0u, 0u, 0u);
      } else {
        int pxi = px - 1;
        int c0s = c0 ^ (((pxi >> 2) & 7) << 3);
        v = *(const uint4*)&tile[pxi * 64 + c0s];
      }
      *(uint4*)(dst + (size_t)i * 8) = v;
    }
  } else {
    // weight pack into MFMA B-fragment order:
    // frag elem i, lane l, k-step kk: k = kk*32+(l>>4)*8+i, tap=k/64, ci=k%64,
    // co = nt*16+(l&15).
    int t = (bid - 8 * PH) * 256 + tid;
    if (t < 18 * 4 * 64) {
      int lane = t & 63;
      int nt   = (t >> 6) & 3;
      int kk   = t >> 8;
      int co   = nt * 16 + (lane & 15);
      int kbase = kk * 32 + ((lane >> 4) << 3);
      short v[8];
#pragma unroll
      for (int i = 0; i < 8; ++i) {
        int k = kbase + i;
        v[i] = f2bf(w_conv[(size_t)(co * 64 + (k & 63)) * 9 + (k >> 6)]);
      }
      *(uint4*)(Bpack + (size_t)t * 8) = *(const uint4*)v;
    }
    int u = t - 18 * 4 * 64;
    if (u >= 0 && u < 18 * 2 * 64) {
      int lane = u & 63;
      int nt   = (u >> 6) & 1;
      int kk   = u >> 7;
      int co   = nt * 16 + (lane & 15);
      int kbase = kk * 32 + ((lane >> 4) << 3);
      short v[8];
#pragma unroll
      for (int i = 0; i < 8; ++i) {
        int k = kbase + i;
        v[i] = (co < 18) ? f2bf(w_off[(size_t)(co * 64 + (k & 63)) * 9 + (k >> 6)]) : (short)0;
      }
      *(uint4*)(wOffPack + (size_t)u * 8) = *(const uint4*)v;
    }
  }
}

// ---------------- K2: fused, window-staged, 3 blocks/CU ---------------------
// LDS map (53,264 B): win [0,46080); offs bf16[64][20] [46080,48640);
// meta int2[64][9] [48640,53248); tf [53248,53252). olds reuses [0,17408).
__global__ __launch_bounds__(256, 3) void k_fused(
    const __hip_bfloat16* __restrict__ xpT, const short* __restrict__ Bpack,
    const short* __restrict__ wOffPack, const float* __restrict__ b_off,
    const float* __restrict__ b_conv, float* __restrict__ out) {
  __shared__ __attribute__((aligned(16))) char shraw[53264];
  char*  win     = shraw;
  __hip_bfloat16* offsB = (__hip_bfloat16*)(shraw + WINB);
  int2*  metaLds = (int2*)(shraw + WINB + 2560);
  int*   tf      = (int*)(shraw + WINB + 2560 + 4608);
  float* olds    = (float*)shraw;

  int bid = blockIdx.x;                      // 8*128*2
  int wh  = bid & 1;
  int h   = (bid >> 1) & 127;
  int n   = bid >> 8;
  int w0  = wh << 6;
  int tid = threadIdx.x, wv = tid >> 6, lane = tid & 63;
  int p = lane & 15, oct = lane >> 4;
  const char* xbB = (const char*)(xpT + (size_t)n * PH * PH * CIN);

  // ---- Stage window: rows h-1..h+3, cols w0-2..w0+69 (360 recs x 128B).
  if (tid == 0) tf[0] = 0;
  for (int i = tid; i < 2880; i += 256) {    // 360 recs * 8 chunks
    int rec = i >> 3, chunk = i & 7;
    int r = rec / WCOLS, c = rec - r * WCOLS;
    int wrow = h - 1 + r, wcol = w0 - 2 + c;
    if ((unsigned)wrow <= 129u && (unsigned)wcol <= 129u) {
      uint4 v = *(const uint4*)(xbB + (size_t)(wrow * 130 + wcol) * 128 + chunk * 16);
      *(uint4*)(win + rec * 128 + ((chunk * 16) ^ ((c & 7) << 4))) = v;
    }
  }
  __syncthreads();

  // ---- P1: offset conv. A from window (LDS), B from global wOffPack.
  {
    f32x4 ao0 = {0.f, 0.f, 0.f, 0.f}, ao1 = ao0;
    const bf16x8* Wo = (const bf16x8*)wOffPack;
    int colbase = 2 + wv * 16 + p;
#pragma unroll
    for (int kk = 0; kk < 18; ++kk) {
      int tap = kk >> 1;
      int ky = tap / 3, kx = tap - (tap / 3) * 3;
      int sub = kk & 1;
      int col = colbase + kx;
      int addr = (1 + ky) * ROWB + col * 128 + ((oct * 16 + sub * 64) ^ ((col & 7) << 4));
      bf16x8 a  = *(const bf16x8*)(win + addr);
      bf16x8 b0 = Wo[(kk * 2 + 0) * 64 + lane];
      bf16x8 b1 = Wo[(kk * 2 + 1) * 64 + lane];
      ao0 = __builtin_amdgcn_mfma_f32_16x16x32_bf16(a, b0, ao0, 0, 0, 0);
      ao1 = __builtin_amdgcn_mfma_f32_16x16x32_bf16(a, b1, ao1, 0, 0, 0);
    }
    int co = lane & 15;
    float bo0 = b_off[co];
#pragma unroll
    for (int r = 0; r < 4; ++r)
      offsB[(wv * 16 + oct * 4 + r) * 20 + co] = __float2bfloat16(ao0[r] + bo0);
    if (co < 2) {
      float bo1 = b_off[16 + co];
#pragma unroll
      for (int r = 0; r < 4; ++r)
        offsB[(wv * 16 + oct * 4 + r) * 20 + 16 + co] = __float2bfloat16(ao1[r] + bo1);
    }
  }
  __syncthreads();

  // ---- P2: sampling metadata (8B/tap) + window-miss bitmask.
  for (int t = tid; t < 576; t += 256) {
    int pix = t / 9, tap = t - pix * 9;
    int ky = tap / 3, kx = tap - (tap / 3) * 3;
    float cx = __bfloat162float(offsB[pix * 20 + tap])     + (float)(w0 + pix + kx);
    float cy = __bfloat162float(offsB[pix * 20 + 9 + tap]) + (float)(h + ky);
    cx = fminf(fmaxf(cx, 0.f), 129.f);
    cy = fminf(fmaxf(cy, 0.f), 129.f);
    float x0f = floorf(cx), y0f = floorf(cy);
    int x0i = (int)x0f, y0i = (int)y0f;
    float wx = cx - x0f, wy = cy - y0f;
    int x1i = min(x0i + 1, 129), y1i = min(y0i + 1, 129);
    int x0r = x0i - w0 + 2, y0r = y0i - h + 1;
    int x1r = x1i - w0 + 2, y1r = y1i - h + 1;
    bool inw = (x0r >= 0) && (y0r >= 0) && (x1r <= WCOLS - 1) && (y1r <= WROWS - 1);
    if (!inw) atomicOr(&tf[0], 1 << tap);
    int dxr = x1i - x0i, dyr = y1i - y0i;            // 0/1
    int rec00 = (y0r * WCOLS + x0r) & 511;
    int w0rd = rec00 | (dxr << 9) | (dyr << 10) | (x0i << 12) | (y0i << 20);
    int w1rd = (unsigned)f2h(wx) | ((unsigned)f2h(wy) << 16);
    metaLds[t] = make_int2(w0rd, w1rd);
  }
  __syncthreads();

  // ---- P3: main conv. v6 runtime loop (pinned: no unroll), fb hoisted.
  f32x4 acc0 = {0.f, 0.f, 0.f, 0.f}, acc1 = acc0, acc2 = acc0, acc3 = acc0;
  const bf16x8* Bp = (const bf16x8*)Bpack;
  int mbase = (wv * 16 + p) * 9;
  int innerQ = oct * 16;
  int fb = tf[0];                            // block-uniform bitmask
#pragma unroll 1
  for (int tap = 0; tap < 9; ++tap) {
    int tfv = (fb >> tap) & 1;
    int2 mt = metaLds[mbase + tap];
    float wx = h2f((unsigned short)(mt.y & 0xffff));
    float wy = h2f((unsigned short)((unsigned)mt.y >> 16));
    float w11 = wx * wy;
    float w01 = wx - w11;
    float w10 = wy - w11;
    float w00 = 1.f - wx - w10;
    int wrd = mt.x;
    int dxr = (wrd >> 9) & 1, dyr = (wrd >> 10) & 1;
    int a00 = 0, a01 = 0, a10 = 0, a11 = 0;
    const char* pb = nullptr;
    int dx = 0, dy = 0;
    if (tfv == 0) {
      int r00 = wrd & 511;
      int r01 = r00 + dxr, r10 = r00 + WCOLS * dyr, r11 = r10 + dxr;
      a00 = r00 * 128 + (innerQ ^ ((r00 & 7) << 4));
      a01 = r01 * 128 + (innerQ ^ ((r01 & 7) << 4));
      a10 = r10 * 128 + (innerQ ^ ((r10 & 7) << 4));
      a11 = r11 * 128 + (innerQ ^ ((r11 & 7) << 4));
    } else {
      int x0i = (wrd >> 12) & 255, y0i = (wrd >> 20) & 255;
      pb = xbB + ((y0i * 130 + x0i) << 7) + (oct << 4);
      dx = dxr << 7;
      dy = dyr * 16640;
    }
#pragma unroll
    for (int half = 0; half < 2; ++half) {
      uint4 q00, q01, q10, q11;
      if (tfv == 0) {
        int hx = half << 6;                  // bit6: swizzle-safe XOR
        q00 = *(const uint4*)(win + (a00 ^ hx));
        q01 = *(const uint4*)(win + (a01 ^ hx));
        q10 = *(const uint4*)(win + (a10 ^ hx));
        q11 = *(const uint4*)(win + (a11 ^ hx));
      } else {
        const char* pc = pb + (half << 6);
        q00 = *(const uint4*)(pc);
        q01 = *(const uint4*)(pc + dx);
        q10 = *(const uint4*)(pc + dy);
        q11 = *(const uint4*)(pc + dx + dy);
      }
      unsigned av[4];
#pragma unroll
      for (int j = 0; j < 4; ++j) {
        unsigned u00 = ((const unsigned*)&q00)[j];
        unsigned u01 = ((const unsigned*)&q01)[j];
        unsigned u10 = ((const unsigned*)&q10)[j];
        unsigned u11 = ((const unsigned*)&q11)[j];
        float sl = blo(u00) * w00 + blo(u01) * w01 + blo(u10) * w10 + blo(u11) * w11;
        float sh = bhi(u00) * w00 + bhi(u01) * w01 + bhi(u10) * w10 + bhi(u11) * w11;
        av[j] = packbf(sl, sh);
      }
      bf16x8 a = __builtin_bit_cast(bf16x8, *(uint4*)av);
      int kk = tap * 2 + half;
      bf16x8 b0 = Bp[(kk * 4 + 0) * 64 + lane];
      bf16x8 b1 = Bp[(kk * 4 + 1) * 64 + lane];
      bf16x8 b2 = Bp[(kk * 4 + 2) * 64 + lane];
      bf16x8 b3 = Bp[(kk * 4 + 3) * 64 + lane];
      acc0 = __builtin_amdgcn_mfma_f32_16x16x32_bf16(a, b0, acc0, 0, 0, 0);
      acc1 = __builtin_amdgcn_mfma_f32_16x16x32_bf16(a, b1, acc1, 0, 0, 0);
      acc2 = __builtin_amdgcn_mfma_f32_16x16x32_bf16(a, b2, acc2, 0, 0, 0);
      acc3 = __builtin_amdgcn_mfma_f32_16x16x32_bf16(a, b3, acc3, 0, 0, 0);
    }
  }
  __syncthreads();

  // ---- P4: epilogue via LDS transpose (pitch 68), coalesced NCHW store.
  int prow0 = wv * 16 + (oct << 2);
#pragma unroll
  for (int r = 0; r < 4; ++r) {
    olds[(prow0 + r) * 68 + p     ] = acc0[r];
    olds[(prow0 + r) * 68 + p + 16] = acc1[r];
    olds[(prow0 + r) * 68 + p + 32] = acc2[r];
    olds[(prow0 + r) * 68 + p + 48] = acc3[r];
  }
  __syncthreads();
  float* ob = out + (size_t)n * COUT * 16384 + (size_t)h * 128 + w0;
  for (int i = tid; i < 4096; i += 256) {
    int co = i >> 6, px = i & 63;
    ob[(size_t)co * 16384 + px] = olds[px * 68 + co] + b_conv[co];
  }
}

// ---------------------------------------------------------------------------
extern "C" void kernel_launch(void* const* d_in, const int* in_sizes, int n_in,
                              void* d_out, int out_size, void* d_ws, size_t ws_size,
                              hipStream_t stream) {
  const float* x      = (const float*)d_in[0];
  const float* w_off  = (const float*)d_in[1];
  const float* b_off  = (const float*)d_in[2];
  const float* w_conv = (const float*)d_in[3];
  const float* b_conv = (const float*)d_in[4];
  float* out = (float*)d_out;

  char* ws = (char*)d_ws;
  __hip_bfloat16* xpT = (__hip_bfloat16*)ws;             // 17,305,600 B
  short* Bpack    = (short*)(ws + 17305600);             //     73,728 B
  short* wOffPack = (short*)(ws + 17305600 + 73728);     //     36,864 B

  k_pad_prep<<<dim3(8 * PH + 27), dim3(256), 0, stream>>>(x, w_off, w_conv,
                                                          xpT, Bpack, wOffPack);
  k_fused<<<dim3(2048), dim3(256), 0, stream>>>(xpT, Bpack, wOffPack, b_off, b_conv, out);
}